// Round 9
// baseline (182.920 us; speedup 1.0000x reference)
//
#include <hip/hip_runtime.h>
#include <hip/hip_fp16.h>
#include <math.h>

#define NFEAT 128
#define NHID  128
#define ALPHA 0.2f

typedef __attribute__((ext_vector_type(8))) short short8;
typedef __attribute__((ext_vector_type(4))) float f32x4;

__device__ inline unsigned int pack_bf16x2_rn(float x, float y) {
    unsigned int bx = __float_as_uint(x), by = __float_as_uint(y);
    bx += 0x7fffu + ((bx >> 16) & 1u);
    by += 0x7fffu + ((by >> 16) & 1u);
    return (bx >> 16) | (by & 0xffff0000u);
}

union Frag { unsigned int u[4]; uint4 v; short8 s; };

// ---------------------------------------------------------------------------
// prep_wt + hist-zero fused. Blocks [0,16): transpose W -> bf16 Wt (32 KB).
// Blocks >=16: zero hist[n] with grid-stride int4 stores.
// ---------------------------------------------------------------------------
__global__ __launch_bounds__(256) void prep_wt_kernel(
    const float* __restrict__ W, unsigned int* __restrict__ Wtg,
    int* __restrict__ hist, int n)
{
    const int t = threadIdx.x;

    if (blockIdx.x >= 16) {
        const int n4     = n >> 2;                       // n % 4 == 0 here
        const int stride = (gridDim.x - 16) << 8;
        int4* h4 = (int4*)hist;
        for (int i = (blockIdx.x - 16) * 256 + t; i < n4; i += stride)
            h4[i] = make_int4(0, 0, 0, 0);
        for (int i = (n4 << 2) + (blockIdx.x - 16) * 256 + t; i < n; i += stride)
            hist[i] = 0;
        return;
    }

    __shared__ float tile[32][33];
    const int kt = blockIdx.x >> 2;
    const int nt = blockIdx.x & 3;

    {
        const int r = t >> 3, c = t & 7;
        const float4 v = *((const float4*)&W[(size_t)(kt * 32 + r) * NHID + nt * 32 + c * 4]);
        tile[r][c * 4 + 0] = v.x; tile[r][c * 4 + 1] = v.y;
        tile[r][c * 4 + 2] = v.z; tile[r][c * 4 + 3] = v.w;
    }
    __syncthreads();

    const int nn = t & 31;
    #pragma unroll
    for (int i = 0; i < 2; ++i) {
        const int kk = (t >> 5) * 2 + i;
        Wtg[(size_t)(nt * 32 + nn) * 64 + kt * 16 + kk] =
            pack_bf16x2_rn(tile[kk * 2][nn], tile[kk * 2 + 1][nn]);
    }
}

// ---------------------------------------------------------------------------
// MFMA bf16 GEMM (block-specialized: last blocks do the edge histogram).
// GEMM: 64 rows/block, 16 rows/wave. A prefetched to registers (8x float4),
// B in XOR-swizzled LDS (stride 64 dwords, kc ^ (nn&15)) -> <=2-way banks.
// ---------------------------------------------------------------------------
__global__ __launch_bounds__(256) void gemm_h_kernel(
    const float* __restrict__ x, const unsigned int* __restrict__ Wtg,
    const float* __restrict__ a, float* __restrict__ h,
    unsigned int* __restrict__ hbu,
    float* __restrict__ s1, float* __restrict__ s2, int n,
    const int* __restrict__ ei, int* __restrict__ hist, int E, int gemm_blocks)
{
    __shared__ unsigned int Wtu[128 * 64];   // 32 KB exactly

    const int t = threadIdx.x;

    if (blockIdx.x >= gemm_blocks) {
        const int E4   = E >> 2;
        const int nthr = (gridDim.x - gemm_blocks) << 8;
        const int g    = (blockIdx.x - gemm_blocks) * 256 + t;
        for (int idx = g; idx < E4; idx += nthr) {
            const int4 s4 = ((const int4*)ei)[idx];
            atomicAdd(&hist[s4.x], 1);
            atomicAdd(&hist[s4.y], 1);
            atomicAdd(&hist[s4.z], 1);
            atomicAdd(&hist[s4.w], 1);
        }
        for (int j = (E4 << 2) + g; j < E; j += nthr) atomicAdd(&hist[ei[j]], 1);
        return;
    }

    #pragma unroll
    for (int i = 0; i < 8; ++i) {
        const int u  = i * 256 + t;
        const uint4 v = ((const uint4*)Wtg)[u];
        const int nn = u >> 4, kc = u & 15;
        *((uint4*)&Wtu[nn * 64 + (kc ^ (nn & 15)) * 4]) = v;
    }

    const int w    = t >> 6;
    const int lane = t & 63;
    const int c    = lane & 15;
    const int quad = lane >> 4;

    const int rowbase = blockIdx.x * 64 + w * 16;

    int arow = rowbase + c; if (arow >= n) arow = n - 1;
    const float4* xp = (const float4*)(x + (size_t)arow * NFEAT);
    float4 xv[8];
    #pragma unroll
    for (int s = 0; s < 4; ++s) {
        xv[2 * s]     = xp[s * 8 + quad * 2];
        xv[2 * s + 1] = xp[s * 8 + quad * 2 + 1];
    }

    float a1v[8], a2v[8];
    #pragma unroll
    for (int tt = 0; tt < 8; ++tt) {
        a1v[tt] = a[tt * 16 + c];
        a2v[tt] = a[NHID + tt * 16 + c];
    }

    f32x4 acc[8];
    #pragma unroll
    for (int tt = 0; tt < 8; ++tt) acc[tt] = (f32x4){0.f, 0.f, 0.f, 0.f};

    __syncthreads();

    #pragma unroll
    for (int s = 0; s < 4; ++s) {
        Frag afr;
        afr.u[0] = pack_bf16x2_rn(xv[2 * s].x,     xv[2 * s].y);
        afr.u[1] = pack_bf16x2_rn(xv[2 * s].z,     xv[2 * s].w);
        afr.u[2] = pack_bf16x2_rn(xv[2 * s + 1].x, xv[2 * s + 1].y);
        afr.u[3] = pack_bf16x2_rn(xv[2 * s + 1].z, xv[2 * s + 1].w);
        const int kc = s * 4 + quad;
        #pragma unroll
        for (int tt = 0; tt < 8; ++tt) {
            Frag bfr;
            bfr.v = *((const uint4*)&Wtu[(tt * 16 + c) * 64 + (kc ^ c) * 4]);
            acc[tt] = __builtin_amdgcn_mfma_f32_16x16x32_bf16(
                afr.s, bfr.s, acc[tt], 0, 0, 0);
        }
    }

    #pragma unroll
    for (int r = 0; r < 4; ++r) {
        const int  row = rowbase + quad * 4 + r;
        const bool ok  = (row < n);
        float p1 = 0.f, p2 = 0.f;
        #pragma unroll
        for (int tt = 0; tt < 8; ++tt) {
            const float v = acc[tt][r];
            if (ok) h[(size_t)row * NHID + tt * 16 + c] = v;
            p1 = fmaf(v, a1v[tt], p1);
            p2 = fmaf(v, a2v[tt], p2);
        }
        #pragma unroll
        for (int p = 0; p < 4; ++p) {
            if (ok) hbu[(size_t)row * 64 + p * 16 + c] =
                pack_bf16x2_rn(acc[2 * p][r], acc[2 * p + 1][r]);
        }
        #pragma unroll
        for (int off = 1; off <= 8; off <<= 1) {
            p1 += __shfl_xor(p1, off, 64);
            p2 += __shfl_xor(p2, off, 64);
        }
        if (ok && c == 0) { s1[row] = p1; s2[row] = p2; }
    }
}

__global__ __launch_bounds__(256) void scan_block_kernel(
    const int* __restrict__ in, int* __restrict__ out, int* __restrict__ bsums, int n)
{
    __shared__ int s[256];
    const int tid = threadIdx.x;
    const int gid = blockIdx.x * 256 + tid;
    const int v = (gid < n) ? in[gid] : 0;
    s[tid] = v;
    __syncthreads();
    #pragma unroll
    for (int off = 1; off < 256; off <<= 1) {
        const int t2 = (tid >= off) ? s[tid - off] : 0;
        __syncthreads();
        s[tid] += t2;
        __syncthreads();
    }
    if (gid < n) out[gid] = s[tid] - v;
    if (tid == 255) bsums[blockIdx.x] = s[255];
}

// Fused level-2 scan + add: every block scans bsums[0..nb) in LDS (nb<=256)
// and applies its own offset.
__global__ __launch_bounds__(256) void scan_add_kernel(
    int* __restrict__ row_ptr, int* __restrict__ cursor,
    const int* __restrict__ bsums, int n, int E, int nb)
{
    __shared__ int s[256];
    const int tid = threadIdx.x;
    s[tid] = (tid < nb) ? bsums[tid] : 0;
    __syncthreads();
    #pragma unroll
    for (int off = 1; off < 256; off <<= 1) {
        const int t2 = (tid >= off) ? s[tid - off] : 0;
        __syncthreads();
        s[tid] += t2;
        __syncthreads();
    }
    const int offset = (blockIdx.x == 0) ? 0 : s[blockIdx.x - 1];
    const int gid = blockIdx.x * 256 + tid;
    if (gid < n) {
        const int v = row_ptr[gid] + offset;
        row_ptr[gid] = v;
        cursor[gid]  = v;
    }
    if (gid == 0) row_ptr[n] = E;
}

// ---------------------------------------------------------------------------
// Scatter: 1 edge/thread, 4-byte records (dst<<16 | fp16(ev)).
// ---------------------------------------------------------------------------
__global__ __launch_bounds__(256) void scatter_kernel(
    const int* __restrict__ ei, const float* __restrict__ s1,
    const float* __restrict__ s2, int* __restrict__ cursor,
    unsigned int* __restrict__ erec, int E)
{
    const int j = blockIdx.x * 256 + threadIdx.x;
    if (j >= E) return;
    const int src = ei[j];
    const int dst = ei[E + j];
    float s = s1[src] + s2[dst];
    s = (s > 0.f) ? s : ALPHA * s;
    const float ev = expf(-s);
    const unsigned int evh = (unsigned int)__half_as_ushort(__float2half(ev));
    const int pos = atomicAdd(&cursor[src], 1);
    erec[pos] = ((unsigned int)dst << 16) | evh;
}

// ---------------------------------------------------------------------------
// Aggregate + finalize: 16-lane group handles TWO nodes with masked 4+4
// batches -> always 8 independent gathers in flight, even for low degrees.
// hbu layout: dword (p*16+c) of a row = pack(col 32p+c, col 32p+16+c).
// ---------------------------------------------------------------------------
__global__ __launch_bounds__(256) void aggregate_kernel(
    const int* __restrict__ row_ptr, const unsigned int* __restrict__ erec,
    const unsigned int* __restrict__ hbu, const float* __restrict__ h,
    float* __restrict__ out, int n)
{
    const int grp = (blockIdx.x * 256 + threadIdx.x) >> 4;
    const int l   = threadIdx.x & 15;
    const int nodeA = grp * 2;
    const int nodeB = nodeA + 1;
    if (nodeA >= n) return;

    const int begA = row_ptr[nodeA];
    const int endA = row_ptr[nodeA + 1];
    int begB = 0, endB = 0;
    if (nodeB < n) { begB = endA; endB = row_ptr[nodeB + 1]; }

    float accA[8], accB[8];
    #pragma unroll
    for (int i = 0; i < 8; ++i) { accA[i] = 0.f; accB[i] = 0.f; }
    float rsA = 0.f, rsB = 0.f;

    const uint4* hbu4 = (const uint4*)hbu;

    const int dA = endA - begA, dB = endB - begB;
    const int iters = max((dA + 3) >> 2, (dB + 3) >> 2);

    #define BL(x) __uint_as_float((x) << 16)
    #define BH(x) __uint_as_float((x) & 0xffff0000u)
    #define ACC4(acc, u, ev)                              \
        acc[0] = fmaf(ev, BL(u.x), acc[0]);               \
        acc[4] = fmaf(ev, BH(u.x), acc[4]);               \
        acc[1] = fmaf(ev, BL(u.y), acc[1]);               \
        acc[5] = fmaf(ev, BH(u.y), acc[5]);               \
        acc[2] = fmaf(ev, BL(u.z), acc[2]);               \
        acc[6] = fmaf(ev, BH(u.z), acc[6]);               \
        acc[3] = fmaf(ev, BL(u.w), acc[3]);               \
        acc[7] = fmaf(ev, BH(u.w), acc[7]);

    for (int it = 0; it < iters; ++it) {
        const int bA = begA + it * 4;
        const int bB = begB + it * 4;
        unsigned int rA[4], rB[4];
        #pragma unroll
        for (int j = 0; j < 4; ++j) rA[j] = (bA + j < endA) ? erec[bA + j] : 0u;
        #pragma unroll
        for (int j = 0; j < 4; ++j) rB[j] = (bB + j < endB) ? erec[bB + j] : 0u;
        uint4 uA[4], uB[4];
        #pragma unroll
        for (int j = 0; j < 4; ++j) uA[j] = hbu4[(size_t)(rA[j] >> 16) * 16 + l];
        #pragma unroll
        for (int j = 0; j < 4; ++j) uB[j] = hbu4[(size_t)(rB[j] >> 16) * 16 + l];
        #pragma unroll
        for (int j = 0; j < 4; ++j) {
            const float evA = __half2float(__ushort_as_half((unsigned short)(rA[j] & 0xffffu)));
            const float evB = __half2float(__ushort_as_half((unsigned short)(rB[j] & 0xffffu)));
            ACC4(accA, uA[j], evA);
            ACC4(accB, uB[j], evB);
            rsA += evA; rsB += evB;
        }
    }
    #undef ACC4
    #undef BL
    #undef BH

    const int p = l >> 2, q = l & 3;

    {
        const float rinv = 1.0f / (rsA + 1e-16f);
        const float4* hp4 = (const float4*)(h + (size_t)nodeA * NHID);
        const float4 ha = hp4[8 * p + q];
        const float4 hb = hp4[8 * p + 4 + q];
        float4 oa, ob;
        float z;
        z = ha.x - accA[0] * rinv; oa.x = (z > 0.f) ? z : (expf(z) - 1.f);
        z = ha.y - accA[1] * rinv; oa.y = (z > 0.f) ? z : (expf(z) - 1.f);
        z = ha.z - accA[2] * rinv; oa.z = (z > 0.f) ? z : (expf(z) - 1.f);
        z = ha.w - accA[3] * rinv; oa.w = (z > 0.f) ? z : (expf(z) - 1.f);
        z = hb.x - accA[4] * rinv; ob.x = (z > 0.f) ? z : (expf(z) - 1.f);
        z = hb.y - accA[5] * rinv; ob.y = (z > 0.f) ? z : (expf(z) - 1.f);
        z = hb.z - accA[6] * rinv; ob.z = (z > 0.f) ? z : (expf(z) - 1.f);
        z = hb.w - accA[7] * rinv; ob.w = (z > 0.f) ? z : (expf(z) - 1.f);
        float4* op = (float4*)(out + (size_t)nodeA * NHID);
        op[8 * p + q]     = oa;
        op[8 * p + 4 + q] = ob;
    }
    if (nodeB < n) {
        const float rinv = 1.0f / (rsB + 1e-16f);
        const float4* hp4 = (const float4*)(h + (size_t)nodeB * NHID);
        const float4 ha = hp4[8 * p + q];
        const float4 hb = hp4[8 * p + 4 + q];
        float4 oa, ob;
        float z;
        z = ha.x - accB[0] * rinv; oa.x = (z > 0.f) ? z : (expf(z) - 1.f);
        z = ha.y - accB[1] * rinv; oa.y = (z > 0.f) ? z : (expf(z) - 1.f);
        z = ha.z - accB[2] * rinv; oa.z = (z > 0.f) ? z : (expf(z) - 1.f);
        z = ha.w - accB[3] * rinv; oa.w = (z > 0.f) ? z : (expf(z) - 1.f);
        z = hb.x - accB[4] * rinv; ob.x = (z > 0.f) ? z : (expf(z) - 1.f);
        z = hb.y - accB[5] * rinv; ob.y = (z > 0.f) ? z : (expf(z) - 1.f);
        z = hb.z - accB[6] * rinv; ob.z = (z > 0.f) ? z : (expf(z) - 1.f);
        z = hb.w - accB[7] * rinv; ob.w = (z > 0.f) ? z : (expf(z) - 1.f);
        float4* op = (float4*)(out + (size_t)nodeB * NHID);
        op[8 * p + q]     = oa;
        op[8 * p + 4 + q] = ob;
    }
}

// ---------------------------------------------------------------------------
extern "C" void kernel_launch(void* const* d_in, const int* in_sizes, int n_in,
                              void* d_out, int out_size, void* d_ws, size_t ws_size,
                              hipStream_t stream) {
    const float* x  = (const float*)d_in[0];
    const float* W  = (const float*)d_in[1];
    const float* a  = (const float*)d_in[2];
    const int*   ei = (const int*)d_in[3];

    const int n = in_sizes[0] / NFEAT;   // 50000
    const int E = in_sizes[3] / 2;       // 640000
    const int nb = (n + 255) / 256;      // 196 (must be <= 256)

    float* out = (float*)d_out;

    // Workspace (4-byte units):
    //   h[n*128] | hbu[n*64] | s1[n] | s2[n] | erec[E] | Wtg[8192] |
    //   hist[n] | bsums[256] | row_ptr[n+1] | cursor[n]
    float*        h     = (float*)d_ws;
    unsigned int* hbu   = (unsigned int*)(h + (size_t)n * NHID);
    float*        s1    = (float*)(hbu + (size_t)n * 64);
    float*        s2    = s1 + n;
    unsigned int* erec  = (unsigned int*)(s2 + n);
    unsigned int* Wtg   = erec + E;
    int*          hist  = (int*)(Wtg + 8192);
    int*          bsums = hist + n;
    int*          row_ptr = bsums + 256;
    int*          cursor  = row_ptr + (n + 1);

    // 1) W transpose + hist zero (fused, independent halves of the grid).
    prep_wt_kernel<<<16 + 50, 256, 0, stream>>>(W, Wtg, hist, n);

    // 2) GEMM + fused histogram (block-specialized).
    const int gemm_blocks = (n + 63) / 64;       // 782
    const int hist_blocks = 128;
    gemm_h_kernel<<<gemm_blocks + hist_blocks, 256, 0, stream>>>(
        x, Wtg, a, h, hbu, s1, s2, n, ei, hist, E, gemm_blocks);

    // 3) per-block scan, 4) fused level-2 scan + add.
    scan_block_kernel<<<nb, 256, 0, stream>>>(hist, row_ptr, bsums, n);
    scan_add_kernel<<<nb, 256, 0, stream>>>(row_ptr, cursor, bsums, n, E, nb);

    // 5) scatter edges into CSR order with precomputed fp16 ev.
    scatter_kernel<<<(E + 255) / 256, 256, 0, stream>>>(ei, s1, s2, cursor, erec, E);

    // 6) gather-aggregate + finalize.
    const int groups = (n + 1) / 2;
    aggregate_kernel<<<(groups * 16 + 255) / 256, 256, 0, stream>>>(
        row_ptr, erec, hbu, h, out, n);
}